// Round 1
// baseline (145.647 us; speedup 1.0000x reference)
//
#include <hip/hip_runtime.h>
#include <hip/hip_bf16.h>
#include <stdint.h>
#include <stddef.h>

#define L_LEN 4096
#define CIN   128
#define COUT  128
#define NB    32
#define KTOT  384            // 3 * CIN, kappa = k*128 + i
#define TN    128            // h-tile per block
#define ROWS  (TN + 2)       // 130 (halo of 1 on each side)

typedef __bf16 bf16x8 __attribute__((ext_vector_type(8)));
typedef float  f32x4  __attribute__((ext_vector_type(4)));

__device__ __forceinline__ uint16_t f2bf(float f) {
    union { float f; uint32_t u; } v; v.f = f;
    return (uint16_t)((v.u + 0x7fffu + ((v.u >> 16) & 1u)) >> 16);  // RNE
}

__device__ __forceinline__ void load_lds16(const void* g, void* l) {
    __builtin_amdgcn_global_load_lds(
        (const __attribute__((address_space(1))) void*)g,
        (__attribute__((address_space(3))) void*)l, 16, 0, 0);
}

// ---- Prologue: combined bf16 weights Wc[b][o][k*128+i] and cbias[b][o] ----
__global__ __launch_bounds__(256) void geps_combine(
    const float* __restrict__ codes, const float* __restrict__ weight,
    const float* __restrict__ Amat,  const float* __restrict__ Bmat,
    const float* __restrict__ bias,  const float* __restrict__ bias_ctx,
    uint16_t* __restrict__ Wc, float* __restrict__ cbias)
{
    int tid = blockIdx.x * 256 + threadIdx.x;
    if (tid < NB * COUT * KTOT) {
        int b   = tid / (COUT * KTOT);
        int rem = tid % (COUT * KTOT);
        int o   = rem / KTOT;
        int kp  = rem % KTOT;         // k*128 + i
        int k   = kp >> 7;
        int i   = kp & 127;
        float cw = 0.f;
        #pragma unroll
        for (int c = 0; c < 2; ++c) {
            float a = Amat[i * 6 + c * 3 + k];
            #pragma unroll
            for (int r = 0; r < 2; ++r)
                cw += a * codes[b * 4 + c * 2 + r] * Bmat[o * 6 + r * 3 + k];
        }
        float val = weight[o * 384 + i * 3 + k] + cw;   // FACTOR = 1
        Wc[tid] = f2bf(val);
    }
    if (tid < NB * COUT) {
        int b = tid >> 7, o = tid & 127;
        float cb = bias[o];
        #pragma unroll
        for (int c = 0; c < 2; ++c)
            cb += codes[b * 4 + c * 2 + c] * bias_ctx[c * 128 + o];
        cbias[tid] = cb;
    }
}

// ---- Main: per-batch GEMM, M=o(128) x N=h(128/block) x K=384, bf16 MFMA ----
__global__ __launch_bounds__(256, 3) void geps_conv(
    const float* __restrict__ in, const uint16_t* __restrict__ Wc,
    const float* __restrict__ cbias, float* __restrict__ out)
{
    // Xt: transposed input tile, element (r,i) at r*128 + (((i>>3)^(r&15))<<3) + (i&7)
    __shared__ uint16_t __attribute__((aligned(16))) Xt[ROWS * 128];
    __shared__ uint16_t __attribute__((aligned(16))) Asm[128 * 32];
    __shared__ float cb[COUT];

    const int tid  = threadIdx.x;
    const int b    = blockIdx.y;
    const int h0   = blockIdx.x * TN;
    const int lane = tid & 63;
    const int wid  = tid >> 6;

    if (tid < COUT) cb[tid] = cbias[b * COUT + tid];

    // --- transpose-load input tile (f32 -> bf16), circular pad via mask ---
    const float* inb = in + (size_t)b * CIN * L_LEN;
    for (int idx = tid; idx < 64 * ROWS; idx += 256) {
        int p  = idx / ROWS;               // i-pair index (i = 2p, 2p+1)
        int r  = idx - p * ROWS;           // LDS row, global h = h0 - 1 + r
        int gh = (h0 - 1 + r) & (L_LEN - 1);
        float x0 = inb[(size_t)(2 * p    ) * L_LEN + gh];
        float x1 = inb[(size_t)(2 * p + 1) * L_LEN + gh];
        uint32_t v = (uint32_t)f2bf(x0) | ((uint32_t)f2bf(x1) << 16);
        int chunk = (p >> 2) ^ (r & 15);
        *(uint32_t*)&Xt[r * 128 + (chunk << 3) + ((2 * p) & 7)] = v;
    }

    const int mq  = (wid & 1) * 64;     // o-offset of this wave
    const int nq  = (wid >> 1) * 64;    // h-offset of this wave
    const int m16 = lane & 15;
    const int q   = lane >> 4;

    f32x4 acc[4][4];
    #pragma unroll
    for (int a = 0; a < 4; ++a)
        #pragma unroll
        for (int c = 0; c < 4; ++c) acc[a][c] = 0.0f;

    const uint16_t* WcB = Wc + (size_t)b * COUT * KTOT;

    for (int t = 0; t < 12; ++t) {
        __syncthreads();                       // prev iter's A reads done
        // stage A: Wc[b][o][32t .. 32t+32) -> Asm[o][0..32), 16B/lane chunks
        #pragma unroll
        for (int p2 = 0; p2 < 2; ++p2) {
            int qq = (p2 * 4 + wid) * 64 + lane;   // chunk id in [0,512)
            int o  = qq >> 2;
            int c4 = qq & 3;
            load_lds16(WcB + o * KTOT + t * 32 + c4 * 8,
                       &Asm[(p2 * 4 + wid) * 512]);  // wave-uniform LDS base
        }
        __syncthreads();                       // staging drained (vmcnt at barrier)

        const int k   = t >> 2;                // kernel tap of this K-step
        const int i0c = (t & 3) * 4;           // i-chunk base = ((t&3)*32)/8
        bf16x8 af[4], bf[4];
        #pragma unroll
        for (int mt = 0; mt < 4; ++mt) {
            int o = mq + mt * 16 + m16;
            af[mt] = *(const bf16x8*)&Asm[o * 32 + q * 8];
        }
        #pragma unroll
        for (int nt = 0; nt < 4; ++nt) {
            int r  = nq + nt * 16 + m16 + k;   // Xt row = h_local + k
            int ch = (i0c + q) ^ (r & 15);
            bf[nt] = *(const bf16x8*)&Xt[r * 128 + (ch << 3)];
        }
        #pragma unroll
        for (int mt = 0; mt < 4; ++mt)
            #pragma unroll
            for (int nt = 0; nt < 4; ++nt)
                acc[mt][nt] = __builtin_amdgcn_mfma_f32_16x16x32_bf16(
                    af[mt], bf[nt], acc[mt][nt], 0, 0, 0);
    }

    // --- epilogue: C/D layout col=lane&15 (h), row=(lane>>4)*4+reg (o) ---
    float* outb = out + (size_t)b * COUT * L_LEN + h0;
    #pragma unroll
    for (int mt = 0; mt < 4; ++mt) {
        #pragma unroll
        for (int reg = 0; reg < 4; ++reg) {
            int o = mq + mt * 16 + q * 4 + reg;
            float bv = cb[o];
            float* orow = outb + (size_t)o * L_LEN;
            #pragma unroll
            for (int nt = 0; nt < 4; ++nt) {
                int h = nq + nt * 16 + m16;
                orow[h] = acc[mt][nt][reg] + bv;
            }
        }
    }
}

extern "C" void kernel_launch(void* const* d_in, const int* in_sizes, int n_in,
                              void* d_out, int out_size, void* d_ws, size_t ws_size,
                              hipStream_t stream) {
    const float* input    = (const float*)d_in[0];
    const float* codes    = (const float*)d_in[1];
    const float* weight   = (const float*)d_in[2];
    const float* Amat     = (const float*)d_in[3];
    const float* Bmat     = (const float*)d_in[4];
    const float* bias     = (const float*)d_in[5];
    const float* bias_ctx = (const float*)d_in[6];
    float* out = (float*)d_out;

    uint16_t* Wc    = (uint16_t*)d_ws;
    float*    cbias = (float*)((char*)d_ws + (size_t)NB * COUT * KTOT * 2);

    geps_combine<<<dim3((NB * COUT * KTOT) / 256), 256, 0, stream>>>(
        codes, weight, Amat, Bmat, bias, bias_ctx, Wc, cbias);
    geps_conv<<<dim3(L_LEN / TN, NB), 256, 0, stream>>>(input, Wc, cbias, out);
}

// Round 2
// 145.581 us; speedup vs baseline: 1.0005x; 1.0005x over previous
//
#include <hip/hip_runtime.h>
#include <hip/hip_bf16.h>
#include <stdint.h>
#include <stddef.h>

#define L_LEN 4096
#define CIN   128
#define COUT  128
#define NB    32
#define KTOT  384            // 3 * CIN, kappa = k*128 + i
#define TN    128            // h-tile per block
#define ROWS  (TN + 2)       // 130 (halo of 1 on each side)

typedef __bf16 bf16x8 __attribute__((ext_vector_type(8)));
typedef float  f32x4  __attribute__((ext_vector_type(4)));

__device__ __forceinline__ uint16_t f2bf(float f) {
    union { float f; uint32_t u; } v; v.f = f;
    return (uint16_t)((v.u + 0x7fffu + ((v.u >> 16) & 1u)) >> 16);  // RNE
}
__device__ __forceinline__ uint32_t pack2(float lo, float hi) {
    return (uint32_t)f2bf(lo) | ((uint32_t)f2bf(hi) << 16);
}

// ---- Prologue: combined bf16 weights Wc[b][o][k*128+i] and cbias[b][o] ----
__global__ __launch_bounds__(256) void geps_combine(
    const float* __restrict__ codes, const float* __restrict__ weight,
    const float* __restrict__ Amat,  const float* __restrict__ Bmat,
    const float* __restrict__ bias,  const float* __restrict__ bias_ctx,
    uint16_t* __restrict__ Wc, float* __restrict__ cbias)
{
    int tid = blockIdx.x * 256 + threadIdx.x;
    if (tid < NB * COUT * KTOT) {
        int b   = tid / (COUT * KTOT);
        int rem = tid % (COUT * KTOT);
        int o   = rem / KTOT;
        int kp  = rem % KTOT;         // k*128 + i
        int k   = kp >> 7;
        int i   = kp & 127;
        float cw = 0.f;
        #pragma unroll
        for (int c = 0; c < 2; ++c) {
            float a = Amat[i * 6 + c * 3 + k];
            #pragma unroll
            for (int r = 0; r < 2; ++r)
                cw += a * codes[b * 4 + c * 2 + r] * Bmat[o * 6 + r * 3 + k];
        }
        float val = weight[o * 384 + i * 3 + k] + cw;   // FACTOR = 1
        Wc[tid] = f2bf(val);
    }
    if (tid < NB * COUT) {
        int b = tid >> 7, o = tid & 127;
        float cb = bias[o];
        #pragma unroll
        for (int c = 0; c < 2; ++c)
            cb += codes[b * 4 + c * 2 + c] * bias_ctx[c * 128 + o];
        cbias[tid] = cb;
    }
}

// ---- Main: per-batch GEMM, M=o(128) x N=h(128/block) x K=384, bf16 MFMA ----
// A-fragments read directly global->VGPR (Wc[b] is 96 KB, L2-resident across
// the 32 h-blocks of a batch) => ZERO barriers in the K-loop.
__global__ __launch_bounds__(256, 4) void geps_conv(
    const float* __restrict__ in, const uint16_t* __restrict__ Wc,
    const float* __restrict__ cbias, float* __restrict__ out)
{
    // Xt: transposed input tile, element (r,i) at r*128 + (((i>>3)^(r&15))<<3) + (i&7)
    __shared__ uint16_t __attribute__((aligned(16))) Xt[ROWS * 128];
    __shared__ float cb[COUT];

    const int tid  = threadIdx.x;
    const int b    = blockIdx.y;
    const int h0   = blockIdx.x * TN;
    const int lane = tid & 63;
    const int wid  = tid >> 6;

    if (tid < COUT) cb[tid] = cbias[b * COUT + tid];

    const float* inb = in + (size_t)b * CIN * L_LEN;

    // --- core transpose: 64 i-pairs x 32 h-quads, float4 loads, u32 LDS writes
    #pragma unroll
    for (int it = 0; it < 8; ++it) {
        int task = it * 256 + tid;
        int p    = task >> 5;            // i-pair (i = 2p, 2p+1)
        int qd   = task & 31;            // h-quad
        const float* r0 = inb + (size_t)(2 * p) * L_LEN + h0 + 4 * qd;
        const float4 a  = *(const float4*)r0;
        const float4 c  = *(const float4*)(r0 + L_LEN);
        const int off   = (2 * p) & 7;
        const int pc    = p >> 2;
        const float av[4] = {a.x, a.y, a.z, a.w};
        const float cv[4] = {c.x, c.y, c.z, c.w};
        #pragma unroll
        for (int j = 0; j < 4; ++j) {
            int r = 1 + 4 * qd + j;      // global h = h0 + 4qd + j
            int chunk = pc ^ (r & 15);
            *(uint32_t*)&Xt[r * 128 + (chunk << 3) + off] = pack2(av[j], cv[j]);
        }
    }
    // --- halo columns r=0 (h0-1) and r=129 (h0+128), circular ---
    if (tid < 128) {
        int p    = tid & 63;
        int side = tid >> 6;             // 0: left, 1: right
        int r    = side ? (ROWS - 1) : 0;
        int gh   = (h0 - 1 + r) & (L_LEN - 1);
        float x0 = inb[(size_t)(2 * p)     * L_LEN + gh];
        float x1 = inb[(size_t)(2 * p + 1) * L_LEN + gh];
        int chunk = (p >> 2) ^ (r & 15);
        *(uint32_t*)&Xt[r * 128 + (chunk << 3) + ((2 * p) & 7)] = pack2(x0, x1);
    }

    const int mq  = (wid & 1) * 64;     // o-offset of this wave
    const int nq  = (wid >> 1) * 64;    // h-offset of this wave
    const int m16 = lane & 15;
    const int q   = lane >> 4;

    f32x4 acc[4][4];
    #pragma unroll
    for (int a = 0; a < 4; ++a)
        #pragma unroll
        for (int c = 0; c < 4; ++c) acc[a][c] = 0.0f;

    const uint16_t* WcB = Wc + (size_t)b * COUT * KTOT;

    __syncthreads();                     // Xt + cb ready; only barrier in kernel

    #pragma unroll
    for (int t = 0; t < 12; ++t) {
        const int k   = t >> 2;          // kernel tap of this K-step
        const int i0c = (t & 3) * 4;     // i-chunk base
        bf16x8 af[4], bf[4];
        #pragma unroll
        for (int mt = 0; mt < 4; ++mt) {
            int o = mq + mt * 16 + m16;
            af[mt] = *(const bf16x8*)(WcB + (size_t)o * KTOT + t * 32 + q * 8);
        }
        #pragma unroll
        for (int nt = 0; nt < 4; ++nt) {
            int r  = nq + nt * 16 + m16 + k;   // Xt row = h_local + k
            int ch = (i0c + q) ^ (r & 15);
            bf[nt] = *(const bf16x8*)&Xt[r * 128 + (ch << 3)];
        }
        #pragma unroll
        for (int mt = 0; mt < 4; ++mt)
            #pragma unroll
            for (int nt = 0; nt < 4; ++nt)
                acc[mt][nt] = __builtin_amdgcn_mfma_f32_16x16x32_bf16(
                    af[mt], bf[nt], acc[mt][nt], 0, 0, 0);
    }

    // --- epilogue: C/D layout col=lane&15 (h), row=(lane>>4)*4+reg (o) ---
    float* outb = out + (size_t)b * COUT * L_LEN + h0;
    #pragma unroll
    for (int mt = 0; mt < 4; ++mt) {
        #pragma unroll
        for (int reg = 0; reg < 4; ++reg) {
            int o = mq + mt * 16 + q * 4 + reg;
            float bv = cb[o];
            float* orow = outb + (size_t)o * L_LEN;
            #pragma unroll
            for (int nt = 0; nt < 4; ++nt) {
                int h = nq + nt * 16 + m16;
                orow[h] = acc[mt][nt][reg] + bv;
            }
        }
    }
}

extern "C" void kernel_launch(void* const* d_in, const int* in_sizes, int n_in,
                              void* d_out, int out_size, void* d_ws, size_t ws_size,
                              hipStream_t stream) {
    const float* input    = (const float*)d_in[0];
    const float* codes    = (const float*)d_in[1];
    const float* weight   = (const float*)d_in[2];
    const float* Amat     = (const float*)d_in[3];
    const float* Bmat     = (const float*)d_in[4];
    const float* bias     = (const float*)d_in[5];
    const float* bias_ctx = (const float*)d_in[6];
    float* out = (float*)d_out;

    uint16_t* Wc    = (uint16_t*)d_ws;
    float*    cbias = (float*)((char*)d_ws + (size_t)NB * COUT * KTOT * 2);

    geps_combine<<<dim3((NB * COUT * KTOT) / 256), 256, 0, stream>>>(
        codes, weight, Amat, Bmat, bias, bias_ctx, Wc, cbias);
    geps_conv<<<dim3(L_LEN / TN, NB), 256, 0, stream>>>(input, Wc, cbias, out);
}

// Round 3
// 140.703 us; speedup vs baseline: 1.0351x; 1.0347x over previous
//
#include <hip/hip_runtime.h>
#include <hip/hip_bf16.h>
#include <stdint.h>
#include <stddef.h>

#define L_LEN 4096
#define CIN   128
#define COUT  128
#define NB    32
#define KTOT  384            // 3 * CIN, kappa = k*128 + i
#define TN    128            // h-tile per block
#define ROWS  (TN + 2)       // 130 (halo of 1 on each side)

typedef __bf16 bf16x8 __attribute__((ext_vector_type(8)));
typedef float  f32x4  __attribute__((ext_vector_type(4)));

__device__ __forceinline__ uint16_t f2bf(float f) {
    union { float f; uint32_t u; } v; v.f = f;
    return (uint16_t)((v.u + 0x7fffu + ((v.u >> 16) & 1u)) >> 16);  // RNE
}
__device__ __forceinline__ uint32_t pack2(float lo, float hi) {
    return (uint32_t)f2bf(lo) | ((uint32_t)f2bf(hi) << 16);
}

// ---- Prologue: combined bf16 weights Wc[b][o][k*128+i] and cbias[b][o] ----
__global__ __launch_bounds__(256) void geps_combine(
    const float* __restrict__ codes, const float* __restrict__ weight,
    const float* __restrict__ Amat,  const float* __restrict__ Bmat,
    const float* __restrict__ bias,  const float* __restrict__ bias_ctx,
    uint16_t* __restrict__ Wc, float* __restrict__ cbias)
{
    int tid = blockIdx.x * 256 + threadIdx.x;
    if (tid < NB * COUT * KTOT) {
        int b   = tid / (COUT * KTOT);
        int rem = tid % (COUT * KTOT);
        int o   = rem / KTOT;
        int kp  = rem % KTOT;         // k*128 + i
        int k   = kp >> 7;
        int i   = kp & 127;
        float cw = 0.f;
        #pragma unroll
        for (int c = 0; c < 2; ++c) {
            float a = Amat[i * 6 + c * 3 + k];
            #pragma unroll
            for (int r = 0; r < 2; ++r)
                cw += a * codes[b * 4 + c * 2 + r] * Bmat[o * 6 + r * 3 + k];
        }
        float val = weight[o * 384 + i * 3 + k] + cw;   // FACTOR = 1
        Wc[tid] = f2bf(val);
    }
    if (tid < NB * COUT) {
        int b = tid >> 7, o = tid & 127;
        float cb = bias[o];
        #pragma unroll
        for (int c = 0; c < 2; ++c)
            cb += codes[b * 4 + c * 2 + c] * bias_ctx[c * 128 + o];
        cbias[tid] = cb;
    }
}

// ---- Main: per-batch GEMM, M=o(128) x N=h(128/block) x K=384, bf16 MFMA ----
// Each wave owns a 32o x 128h quadrant; its ENTIRE A-quadrant (af[12][2],
// 96 VGPRs) is loaded global->VGPR up-front, latency hidden under the
// input-transpose phase. K-loop = ds_read_b128 + MFMA only, no barriers.
__global__ __launch_bounds__(256, 2) void geps_conv(
    const float* __restrict__ in, const uint16_t* __restrict__ Wc,
    const float* __restrict__ cbias, float* __restrict__ out)
{
    // Xt: transposed input tile, element (r,i) at r*128 + (((i>>3)^(r&15))<<3) + (i&7)
    __shared__ uint16_t __attribute__((aligned(16))) Xt[ROWS * 128];
    __shared__ float cb[COUT];

    const int tid  = threadIdx.x;
    const int b    = blockIdx.y;
    const int h0   = blockIdx.x * TN;
    const int lane = tid & 63;
    const int wid  = tid >> 6;
    const int m16  = lane & 15;
    const int q    = lane >> 4;
    const int mq   = wid * 32;           // wave's o-offset (4 waves x 32 o)

    if (tid < COUT) cb[tid] = cbias[b * COUT + tid];

    const uint16_t* WcB = Wc + (size_t)b * COUT * KTOT;
    const float*    inb = in + (size_t)b * CIN * L_LEN;

    // --- A-fragments for the whole K range: issued first, L2 latency hides
    //     under the transpose phase's HBM loads.
    bf16x8 af[12][2];
    #pragma unroll
    for (int t = 0; t < 12; ++t)
        #pragma unroll
        for (int mt = 0; mt < 2; ++mt)
            af[t][mt] = *(const bf16x8*)(WcB +
                (size_t)(mq + mt * 16 + m16) * KTOT + t * 32 + q * 8);

    // --- core transpose: 32 i-quads x 32 h-quads, float4 loads, uint2 writes
    #pragma unroll
    for (int it = 0; it < 4; ++it) {
        int task = it * 256 + tid;       // 1024 tasks
        int p4   = task >> 5;            // i-quad (i = 4p4 .. 4p4+3)
        int qd   = task & 31;            // h-quad
        const float* r0 = inb + (size_t)(4 * p4) * L_LEN + h0 + 4 * qd;
        float4 a0 = *(const float4*)(r0);
        float4 a1 = *(const float4*)(r0 + L_LEN);
        float4 a2 = *(const float4*)(r0 + 2 * L_LEN);
        float4 a3 = *(const float4*)(r0 + 3 * L_LEN);
        const int off = (4 * p4) & 7;    // 0 or 4
        const int pc  = p4 >> 1;         // i-chunk
        const float v0[4] = {a0.x, a0.y, a0.z, a0.w};
        const float v1[4] = {a1.x, a1.y, a1.z, a1.w};
        const float v2[4] = {a2.x, a2.y, a2.z, a2.w};
        const float v3[4] = {a3.x, a3.y, a3.z, a3.w};
        #pragma unroll
        for (int j = 0; j < 4; ++j) {
            int r  = 1 + 4 * qd + j;     // global h = h0 + 4qd + j
            int ch = pc ^ (r & 15);
            uint2 w;
            w.x = pack2(v0[j], v1[j]);
            w.y = pack2(v2[j], v3[j]);
            *(uint2*)&Xt[r * 128 + (ch << 3) + off] = w;
        }
    }
    // --- halo columns r=0 (h0-1) and r=129 (h0+128), circular ---
    if (tid < 128) {
        int p    = tid & 63;             // i-pair
        int side = tid >> 6;             // 0: left, 1: right
        int r    = side ? (ROWS - 1) : 0;
        int gh   = (h0 - 1 + r) & (L_LEN - 1);
        float x0 = inb[(size_t)(2 * p)     * L_LEN + gh];
        float x1 = inb[(size_t)(2 * p + 1) * L_LEN + gh];
        int chunk = (p >> 2) ^ (r & 15);
        *(uint32_t*)&Xt[r * 128 + (chunk << 3) + ((2 * p) & 7)] = pack2(x0, x1);
    }

    f32x4 acc[2][8];
    #pragma unroll
    for (int a = 0; a < 2; ++a)
        #pragma unroll
        for (int c = 0; c < 8; ++c) acc[a][c] = 0.0f;

    __syncthreads();                     // Xt + cb ready; only barrier

    #pragma unroll
    for (int t = 0; t < 12; ++t) {
        const int k   = t >> 2;          // kernel tap of this K-step
        const int i0c = (t & 3) * 4;     // i-chunk base
        bf16x8 bf[8];
        #pragma unroll
        for (int nt = 0; nt < 8; ++nt) {
            int r  = nt * 16 + m16 + k;  // Xt row = h_local + k
            int ch = (i0c + q) ^ (r & 15);
            bf[nt] = *(const bf16x8*)&Xt[r * 128 + (ch << 3)];
        }
        #pragma unroll
        for (int mt = 0; mt < 2; ++mt)
            #pragma unroll
            for (int nt = 0; nt < 8; ++nt)
                acc[mt][nt] = __builtin_amdgcn_mfma_f32_16x16x32_bf16(
                    af[t][mt], bf[nt], acc[mt][nt], 0, 0, 0);
    }

    // --- epilogue: C/D layout col=lane&15 (h), row=(lane>>4)*4+reg (o) ---
    float* outb = out + (size_t)b * COUT * L_LEN + h0;
    #pragma unroll
    for (int mt = 0; mt < 2; ++mt) {
        #pragma unroll
        for (int reg = 0; reg < 4; ++reg) {
            int o = mq + mt * 16 + q * 4 + reg;
            float bv = cb[o];
            float* orow = outb + (size_t)o * L_LEN;
            #pragma unroll
            for (int nt = 0; nt < 8; ++nt) {
                int h = nt * 16 + m16;
                orow[h] = acc[mt][nt][reg] + bv;
            }
        }
    }
}

extern "C" void kernel_launch(void* const* d_in, const int* in_sizes, int n_in,
                              void* d_out, int out_size, void* d_ws, size_t ws_size,
                              hipStream_t stream) {
    const float* input    = (const float*)d_in[0];
    const float* codes    = (const float*)d_in[1];
    const float* weight   = (const float*)d_in[2];
    const float* Amat     = (const float*)d_in[3];
    const float* Bmat     = (const float*)d_in[4];
    const float* bias     = (const float*)d_in[5];
    const float* bias_ctx = (const float*)d_in[6];
    float* out = (float*)d_out;

    uint16_t* Wc    = (uint16_t*)d_ws;
    float*    cbias = (float*)((char*)d_ws + (size_t)NB * COUT * KTOT * 2);

    geps_combine<<<dim3((NB * COUT * KTOT) / 256), 256, 0, stream>>>(
        codes, weight, Amat, Bmat, bias, bias_ctx, Wc, cbias);
    geps_conv<<<dim3(L_LEN / TN, NB), 256, 0, stream>>>(input, Wc, cbias, out);
}